// Round 16
// baseline (6535.416 us; speedup 1.0000x reference)
//
#include <hip/hip_runtime.h>
#include <math.h>

#define B_ 8
#define N_ 16384
#define M_ 4096
#define D_ 512
#define TPB 512
#define PPT 32          // N_ / TPB points per thread

#define FEAT_SZ (B_ * M_ * D_)          // 16777216
#define COFF FEAT_SZ                    // coords_out
#define TOFF (FEAT_SZ + 2 * B_ * M_)    // times_out
#define POFF (TOFF + B_ * M_)           // pol_out

#define R32(F) F(0) F(1) F(2) F(3) F(4) F(5) F(6) F(7) \
               F(8) F(9) F(10) F(11) F(12) F(13) F(14) F(15) \
               F(16) F(17) F(18) F(19) F(20) F(21) F(22) F(23) \
               F(24) F(25) F(26) F(27) F(28) F(29) F(30) F(31)
// descending order: select chains end at the SMALLEST index (first occurrence)
#define R32D(F) F(31) F(30) F(29) F(28) F(27) F(26) F(25) F(24) \
                F(23) F(22) F(21) F(20) F(19) F(18) F(17) F(16) \
                F(15) F(14) F(13) F(12) F(11) F(10) F(9) F(8) \
                F(7) F(6) F(5) F(4) F(3) F(2) F(1) F(0)

// DPP row ctrl codes: row_shr:n = 0x110|n, row_bcast15 = 0x142, row_bcast31 = 0x143.
template <int CTRL>
__device__ __forceinline__ float dpp_max_step(float x) {
    const int y = __builtin_amdgcn_update_dpp(0, __float_as_int(x),
                                              CTRL, 0xf, 0xf, true);
    return fmaxf(x, __int_as_float(y));   // invalid lanes read 0; s values > 0
}

// ---------------------------------------------------------------------------
// Kernel 1: farthest point sampling, one block per batch.
//
// r16 structural change vs r15: TPB 1024->512, PPT 16->32, waves_per_eu(2,2).
// Rationale: at 4 waves/EU the VGPR budget (128) never let the allocator keep
// the point set resident (observed VGPR 48-64 across r3-r15; reload traffic
// co-limited with VALU issue at ~97% busy). At 2 waves/EU the budget is 256:
// the full 32-point state (128 floats + temps ~ 160 VGPR) fits WITH SLACK, so
// residency is now the allocator's cheapest legal choice. Issue work is
// conserved (256 update-inst x 2 waves/SIMD = same), but per-wave overhead
// (sqrt, DPP reduce, 8-entry scan, tail) halves in aggregate.
//
// Bit-exact chain (verified r2-r15): d2 = fma(dz,dz, fma(dx,dx, dy*dy));
// s = sqrt_rn(fadd_rn(d2,1e-8)). Min in d2 domain (commutes with monotone
// sqrt chain). Value phase: bm = max_i m_i (8 VALU/pt, no index tracking);
// s_local = s(bm); DPP wave max; bar1; all threads scan 8 wave maxima.
// Index phase (winner threads only, execz-skipped elsewhere):
//   common: min slot with m_i == bm exactly (descending select, carries pt_i);
//   rare (>=2 slots within 32-ulp window of bm): sqrt-verify window slots
//           (sqrt-collapse ties), min flat index with s == s_local.
//   publish: ONE LDS atomicMin of (flat<<32 | t_bits) -> min flat index wins
//   (jnp.argmax first-occurrence), its t rides as payload.
// bar2; all threads: gi/lt from the key, lx/ly from cxy[gi] (LDS read).
// ---------------------------------------------------------------------------
__global__ __launch_bounds__(TPB)
__attribute__((amdgpu_waves_per_eu(2, 2)))
void fps_kernel(
    const float* __restrict__ coords, const float* __restrict__ times,
    int* __restrict__ idx_out)
{
    const int b = blockIdx.x;
    const int t = threadIdx.x;
    const float* cb = coords + (size_t)b * N_ * 2;
    const float* tb = times + (size_t)b * N_;

    __shared__ float2 cxy[N_];                        // winner-lookup copy
    __shared__ __align__(16) float red_s[8];          // per-wave value maxima
    __shared__ unsigned long long nxt[2];             // winner key, parity dbuf

#define DECLV(i) float px##i, py##i, pt##i, m##i;
    R32(DECLV)
#undef DECLV

#define LOADV(i) { const int gi = (i) * TPB + t;                              \
        const float2 c2 = *(const float2*)(cb + 2 * (size_t)gi);              \
        cxy[gi] = c2; px##i = c2.x; py##i = c2.y; pt##i = tb[gi];             \
        m##i = INFINITY; }
    R32(LOADV)
#undef LOADV

    // volatile pins: unrepeatable defs (non-volatile pins are
    // rematerializable — r7's failure mode)
#define PINV(i) asm volatile("" : "+v"(px##i), "+v"(py##i), "+v"(pt##i));
    R32(PINV)
#undef PINV

    if (t == 0) {
        idx_out[b * M_] = 0;                          // deterministic seed
        nxt[0] = ~0ull; nxt[1] = ~0ull;
    }
    float lx = cb[0], ly = cb[1], lt = tb[0];
    __syncthreads();

    const int wave = t >> 6;
    const int lane = t & 63;

    for (int k = 1; k < M_; ++k) {
        const int par = k & 1;
        float bm = -INFINITY;

        // ---- value phase: pure-register d2-min update + running max
#define UPDV(i) {                                                             \
        const float dx = px##i - lx;                                          \
        const float dy = py##i - ly;                                          \
        const float dz = pt##i - lt;                                          \
        const float d2 = __fmaf_rn(dz, dz, __fmaf_rn(dx, dx,                  \
                                                     __fmul_rn(dy, dy)));     \
        m##i = fminf(m##i, d2);                                               \
        bm = fmaxf(bm, m##i); }
        R32(UPDV)
#undef UPDV

        const float s_local = __fsqrt_rn(__fadd_rn(bm, 1e-8f));

        // DPP wave-max (VALU pipe): lane 63 ends with the wave max
        float v = s_local;
        v = dpp_max_step<0x111>(v);   // row_shr:1
        v = dpp_max_step<0x112>(v);   // row_shr:2
        v = dpp_max_step<0x114>(v);   // row_shr:4
        v = dpp_max_step<0x118>(v);   // row_shr:8
        v = dpp_max_step<0x142>(v);   // row_bcast:15
        v = dpp_max_step<0x143>(v);   // row_bcast:31
        if (lane == 63) red_s[wave] = v;
        __syncthreads();                              // bar1

        if (t == 0) nxt[par ^ 1] = ~0ull;             // reset other parity

        // all threads: block max from 8 floats (vector reads + max tree)
        const float4* rp = (const float4*)red_s;
        const float4 r0 = rp[0], r1 = rp[1];
        const float s_star = fmaxf(
            fmaxf(fmaxf(r0.x, r0.y), fmaxf(r0.z, r0.w)),
            fmaxf(fmaxf(r1.x, r1.y), fmaxf(r1.z, r1.w)));

        // ---- index phase: winners only (execz-skipped in non-winner waves)
        if (s_local == s_star) {
            // common case: min flat index with m_i == bm exactly, t rides
            int   fj = 0x7fffffff;
            float ft = 0.f;
#define SELV(i) if (m##i == bm) { fj = (i) * TPB + t; ft = pt##i; }
            R32D(SELV)
#undef SELV

            // sqrt-collapse guard: >=2 slots within 32 ulps of bm?
            const unsigned bmu = __float_as_uint(bm);
            const float thresh = __uint_as_float(bmu >= 32u ? bmu - 32u : 0u);
            float cnt = 0.f;
#define CNTV(i) cnt += (m##i >= thresh) ? 1.0f : 0.0f;
            R32(CNTV)
#undef CNTV
            if (cnt > 1.5f) {   // rare: verify window slots in s domain
#define FIXV(i) if (m##i >= thresh) {                                         \
                const float si = __fsqrt_rn(__fadd_rn(m##i, 1e-8f));          \
                if (si == s_local) { fj = (i) * TPB + t; ft = pt##i; } }
                R32D(FIXV)
#undef FIXV
            }
            atomicMin(&nxt[par],
                      (((unsigned long long)(unsigned)fj) << 32) |
                      __float_as_uint(ft));
        }
        __syncthreads();                              // bar2

        const unsigned long long wk = nxt[par];
        const int gi = (int)(wk >> 32);
        lt = __uint_as_float((unsigned)wk);
        const float2 wv = cxy[gi];                    // LDS broadcast read
        lx = wv.x; ly = wv.y;
        if (t == 0) idx_out[b * M_ + k] = gi;
    }
}

// ---------------------------------------------------------------------------
// Kernel 2: gather coords/times/polarities at sampled indices.
// ---------------------------------------------------------------------------
__global__ __launch_bounds__(256) void gather_kernel(
    const float* __restrict__ coords, const float* __restrict__ times,
    const float* __restrict__ pol, const int* __restrict__ idx,
    float* __restrict__ out)
{
    int i = blockIdx.x * 256 + threadIdx.x;       // 0 .. B_*M_-1
    if (i >= B_ * M_) return;
    int b = i >> 12;                              // / M_
    int g = b * N_ + idx[i];
    float2 c2 = *(const float2*)(coords + 2 * (size_t)g);
    *(float2*)(out + COFF + 2 * (size_t)i) = c2;
    out[TOFF + i] = times[g];
    out[POFF + i] = pol[g];
}

// ---------------------------------------------------------------------------
// Kernel 3: gathered GEMM + bias.  C[row, o] = features[src(row), :] . W[o, :]
// ---------------------------------------------------------------------------
#define BM 32
#define BN 128
#define BK 32

__global__ __launch_bounds__(256) void proj_kernel(
    const float* __restrict__ features, const float* __restrict__ W,
    const float* __restrict__ bias, const int* __restrict__ idx,
    float* __restrict__ out)
{
    __shared__ float a_lds[BK][BM + 4];
    __shared__ float w_lds[BK][BN];
    __shared__ int   src[BM];

    const int t = threadIdx.x;
    const int rowBase = blockIdx.x * BM;
    const int oBase = blockIdx.y * BN;

    if (t < BM) {
        int row = rowBase + t;
        int b = row >> 12;                // / M_
        src[t] = b * N_ + idx[row];
    }
    __syncthreads();

    const int rt = t >> 5;        // 0..7   -> rows rt*4..rt*4+3
    const int ot = t & 31;        // 0..31  -> outs ot*4..ot*4+3
    const int lr = t >> 3;        // 0..31  staging row / out
    const int lk = (t & 7) * 4;   // 0,4,...,28 staging k

    float c[4][4] = {};

    for (int kc = 0; kc < D_; kc += BK) {
        {
            float4 v = *(const float4*)(features + (size_t)src[lr] * D_ + kc + lk);
            a_lds[lk + 0][lr] = v.x; a_lds[lk + 1][lr] = v.y;
            a_lds[lk + 2][lr] = v.z; a_lds[lk + 3][lr] = v.w;
        }
#pragma unroll
        for (int p = 0; p < 4; ++p) {
            int o = p * 32 + lr;
            float4 v = *(const float4*)(W + (size_t)(oBase + o) * D_ + kc + lk);
            w_lds[lk + 0][o] = v.x; w_lds[lk + 1][o] = v.y;
            w_lds[lk + 2][o] = v.z; w_lds[lk + 3][o] = v.w;
        }
        __syncthreads();

#pragma unroll
        for (int k = 0; k < BK; ++k) {
            float4 af = *(const float4*)&a_lds[k][rt * 4];
            float4 wf = *(const float4*)&w_lds[k][ot * 4];
            float av[4] = { af.x, af.y, af.z, af.w };
            float wv[4] = { wf.x, wf.y, wf.z, wf.w };
#pragma unroll
            for (int ri = 0; ri < 4; ++ri)
#pragma unroll
                for (int oi = 0; oi < 4; ++oi)
                    c[ri][oi] = fmaf(av[ri], wv[oi], c[ri][oi]);
        }
        __syncthreads();
    }

    float4 bv = *(const float4*)(bias + oBase + ot * 4);
    float bvv[4] = { bv.x, bv.y, bv.z, bv.w };
#pragma unroll
    for (int ri = 0; ri < 4; ++ri) {
        int row = rowBase + rt * 4 + ri;
        float4 o4;
        o4.x = c[ri][0] + bvv[0];
        o4.y = c[ri][1] + bvv[1];
        o4.z = c[ri][2] + bvv[2];
        o4.w = c[ri][3] + bvv[3];
        *(float4*)(out + (size_t)row * D_ + oBase + ot * 4) = o4;
    }
}

// ---------------------------------------------------------------------------
// Kernel 4: LayerNorm in place over the proj output. One wave per row.
// ---------------------------------------------------------------------------
__global__ __launch_bounds__(256) void ln_kernel(
    float* __restrict__ out, const float* __restrict__ gamma,
    const float* __restrict__ beta)
{
    const int w = threadIdx.x >> 6;
    const int lane = threadIdx.x & 63;
    const size_t row = (size_t)blockIdx.x * 4 + w;
    float* p = out + row * D_;

    float4 v0 = *(const float4*)(p + lane * 8);
    float4 v1 = *(const float4*)(p + lane * 8 + 4);
    float x[8] = { v0.x, v0.y, v0.z, v0.w, v1.x, v1.y, v1.z, v1.w };

    float sum = 0.f;
#pragma unroll
    for (int i = 0; i < 8; ++i) sum += x[i];
#pragma unroll
    for (int off = 1; off < 64; off <<= 1) sum += __shfl_xor(sum, off);
    const float mu = sum * (1.0f / 512.0f);

    float sq = 0.f;
#pragma unroll
    for (int i = 0; i < 8; ++i) { float d = x[i] - mu; sq = fmaf(d, d, sq); }
#pragma unroll
    for (int off = 1; off < 64; off <<= 1) sq += __shfl_xor(sq, off);
    const float inv = rsqrtf(sq * (1.0f / 512.0f) + 1e-5f);

    float4 g0 = *(const float4*)(gamma + lane * 8);
    float4 g1 = *(const float4*)(gamma + lane * 8 + 4);
    float4 b0 = *(const float4*)(beta + lane * 8);
    float4 b1 = *(const float4*)(beta + lane * 8 + 4);
    float g[8] = { g0.x, g0.y, g0.z, g0.w, g1.x, g1.y, g1.z, g1.w };
    float be[8] = { b0.x, b0.y, b0.z, b0.w, b1.x, b1.y, b1.z, b1.w };

    float y[8];
#pragma unroll
    for (int i = 0; i < 8; ++i) y[i] = fmaf((x[i] - mu) * inv, g[i], be[i]);

    float4 o0 = { y[0], y[1], y[2], y[3] };
    float4 o1 = { y[4], y[5], y[6], y[7] };
    *(float4*)(p + lane * 8) = o0;
    *(float4*)(p + lane * 8 + 4) = o1;
}

// ---------------------------------------------------------------------------
extern "C" void kernel_launch(void* const* d_in, const int* in_sizes, int n_in,
                              void* d_out, int out_size, void* d_ws, size_t ws_size,
                              hipStream_t stream)
{
    const float* features   = (const float*)d_in[0];
    const float* coords     = (const float*)d_in[1];
    const float* times      = (const float*)d_in[2];
    const float* polarities = (const float*)d_in[3];
    const float* W          = (const float*)d_in[4];
    const float* bias       = (const float*)d_in[5];
    const float* gamma      = (const float*)d_in[6];
    const float* beta       = (const float*)d_in[7];
    float* out = (float*)d_out;

    int* idx = (int*)d_ws;                        // B_*M_ ints = 128 KiB scratch

    fps_kernel<<<B_, TPB, 0, stream>>>(coords, times, idx);

    gather_kernel<<<(B_ * M_ + 255) / 256, 256, 0, stream>>>(
        coords, times, polarities, idx, out);

    dim3 pgrid(B_ * M_ / BM, D_ / BN);            // (1024, 4)
    proj_kernel<<<pgrid, 256, 0, stream>>>(features, W, bias, idx, out);

    ln_kernel<<<B_ * M_ / 4, 256, 0, stream>>>(out, gamma, beta);
}

// Round 17
// 5762.416 us; speedup vs baseline: 1.1341x; 1.1341x over previous
//
#include <hip/hip_runtime.h>
#include <math.h>

#define B_ 8
#define N_ 16384
#define M_ 4096
#define D_ 512
#define TPB 1024
#define PPT 16          // N_ / TPB points per thread

#define FEAT_SZ (B_ * M_ * D_)          // 16777216
#define COFF FEAT_SZ                    // coords_out
#define TOFF (FEAT_SZ + 2 * B_ * M_)    // times_out
#define POFF (TOFF + B_ * M_)           // pol_out

#define R16(F) F(0) F(1) F(2) F(3) F(4) F(5) F(6) F(7) \
               F(8) F(9) F(10) F(11) F(12) F(13) F(14) F(15)
// descending order: select chains end at the SMALLEST index (first occurrence)
#define R16D(F) F(15) F(14) F(13) F(12) F(11) F(10) F(9) F(8) \
                F(7) F(6) F(5) F(4) F(3) F(2) F(1) F(0)

// DPP row ctrl codes: row_shr:n = 0x110|n, row_bcast15 = 0x142, row_bcast31 = 0x143.
template <int CTRL>
__device__ __forceinline__ float dpp_max_step(float x) {
    const int y = __builtin_amdgcn_update_dpp(0, __float_as_int(x),
                                              CTRL, 0xf, 0xf, true);
    return fmaxf(x, __int_as_float(y));   // invalid lanes read 0; s values > 0
}

// ---------------------------------------------------------------------------
// Kernel 1: farthest point sampling, one block per batch.  [r15 revert — best]
//
// Measured design-space summary (r3-r16): this structure (1024 thr, PPT=16,
// 4 waves/EU, volatile-pinned coords + LDS winner-lookup copy) is the optimum.
// - r16 (512 thr / PPT=32 / 2 waves/EU): VGPR 56->92 but dur +16% — residency
//   still incomplete AND half the TLP lost. No (waves, residency) point wins.
// - r11-r13 (Morton + exact bbox pruning): VALU halved, wall time rose —
//   latency-bound lone-wave + barrier skeleton.
// - r8 (LDS-resident): no change; r5-r7 (register forcing at 4 waves): VGPR
//   pinned ~52-64 by the allocator's occupancy target.
// Floor arithmetic: 4095 serial argmax rounds x ~3180 cy (issue-saturated:
// 97% per-active-CU VALUBusy, 8 CUs, serial dependency forbids more CUs
// without >1000cy cross-CU sync per round) ~= 5.4 ms.
//
// Bit-exact chain (verified r2-r15): d2 = fma(dz,dz, fma(dx,dx, dy*dy));
// s = sqrt_rn(fadd_rn(d2,1e-8)). Min in d2 domain (commutes with monotone
// sqrt chain). Value phase: bm = max_i m_i (8 VALU/pt); s_local = s(bm);
// DPP wave max; bar1; all threads scan 16 wave maxima.
// Index phase (winner threads only): min slot with m_i == bm (descending
// select, carries pt_i); rare sqrt-collapse ulp-window fixup; publish ONE
// LDS atomicMin of (flat<<32 | t_bits) -> min flat index wins (jnp.argmax
// first-occurrence). bar2; gi/lt from key, lx/ly from cxy[gi].
// ---------------------------------------------------------------------------
__global__ __launch_bounds__(TPB)
__attribute__((amdgpu_waves_per_eu(4, 4)))
void fps_kernel(
    const float* __restrict__ coords, const float* __restrict__ times,
    int* __restrict__ idx_out)
{
    const int b = blockIdx.x;
    const int t = threadIdx.x;
    const float* cb = coords + (size_t)b * N_ * 2;
    const float* tb = times + (size_t)b * N_;

    __shared__ float2 cxy[N_];                        // winner-lookup copy
    __shared__ __align__(16) float red_s[16];         // per-wave value maxima
    __shared__ unsigned long long nxt[2];             // winner key, parity dbuf

#define DECLV(i) float px##i, py##i, pt##i, m##i;
    R16(DECLV)
#undef DECLV

#define LOADV(i) { const int gi = (i) * TPB + t;                              \
        const float2 c2 = *(const float2*)(cb + 2 * (size_t)gi);              \
        cxy[gi] = c2; px##i = c2.x; py##i = c2.y; pt##i = tb[gi];             \
        m##i = INFINITY; }
    R16(LOADV)
#undef LOADV

    // VOLATILE pins: unrepeatable defs -> values must stay in VGPRs
    // (non-volatile asm pins are rematerializable — the r7 failure mode).
#define PINV(i) asm volatile("" : "+v"(px##i), "+v"(py##i), "+v"(pt##i));
    R16(PINV)
#undef PINV

    if (t == 0) {
        idx_out[b * M_] = 0;                          // deterministic seed
        nxt[0] = ~0ull; nxt[1] = ~0ull;
    }
    float lx = cb[0], ly = cb[1], lt = tb[0];
    __syncthreads();

    const int wave = t >> 6;
    const int lane = t & 63;

    for (int k = 1; k < M_; ++k) {
        const int par = k & 1;
        float bm = -INFINITY;

        // ---- value phase: pure-register d2-min update + running max
#define UPDV(i) {                                                             \
        const float dx = px##i - lx;                                          \
        const float dy = py##i - ly;                                          \
        const float dz = pt##i - lt;                                          \
        const float d2 = __fmaf_rn(dz, dz, __fmaf_rn(dx, dx,                  \
                                                     __fmul_rn(dy, dy)));     \
        m##i = fminf(m##i, d2);                                               \
        bm = fmaxf(bm, m##i); }
        R16(UPDV)
#undef UPDV

        const float s_local = __fsqrt_rn(__fadd_rn(bm, 1e-8f));

        // DPP wave-max (VALU pipe): lane 63 ends with the wave max
        float v = s_local;
        v = dpp_max_step<0x111>(v);   // row_shr:1
        v = dpp_max_step<0x112>(v);   // row_shr:2
        v = dpp_max_step<0x114>(v);   // row_shr:4
        v = dpp_max_step<0x118>(v);   // row_shr:8
        v = dpp_max_step<0x142>(v);   // row_bcast:15
        v = dpp_max_step<0x143>(v);   // row_bcast:31
        if (lane == 63) red_s[wave] = v;
        __syncthreads();                              // bar1

        if (t == 0) nxt[par ^ 1] = ~0ull;             // reset other parity

        // all threads: block max from 16 floats (vector reads + max tree)
        const float4* rp = (const float4*)red_s;
        const float4 r0 = rp[0], r1 = rp[1], r2 = rp[2], r3 = rp[3];
        const float s_star = fmaxf(
            fmaxf(fmaxf(fmaxf(r0.x, r0.y), fmaxf(r0.z, r0.w)),
                  fmaxf(fmaxf(r1.x, r1.y), fmaxf(r1.z, r1.w))),
            fmaxf(fmaxf(fmaxf(r2.x, r2.y), fmaxf(r2.z, r2.w)),
                  fmaxf(fmaxf(r3.x, r3.y), fmaxf(r3.z, r3.w))));

        // ---- index phase: winners only (execz-skipped in non-winner waves)
        if (s_local == s_star) {
            // common case: min flat index with m_i == bm exactly, t rides
            int   fj = 0x7fffffff;
            float ft = 0.f;
#define SELV(i) if (m##i == bm) { fj = (i) * TPB + t; ft = pt##i; }
            R16D(SELV)
#undef SELV

            // sqrt-collapse guard: >=2 slots within 32 ulps of bm?
            const unsigned bmu = __float_as_uint(bm);
            const float thresh = __uint_as_float(bmu >= 32u ? bmu - 32u : 0u);
            float cnt = 0.f;
#define CNTV(i) cnt += (m##i >= thresh) ? 1.0f : 0.0f;
            R16(CNTV)
#undef CNTV
            if (cnt > 1.5f) {   // rare: verify window slots in s domain
#define FIXV(i) if (m##i >= thresh) {                                         \
                const float si = __fsqrt_rn(__fadd_rn(m##i, 1e-8f));          \
                if (si == s_local) { fj = (i) * TPB + t; ft = pt##i; } }
                R16D(FIXV)
#undef FIXV
            }
            atomicMin(&nxt[par],
                      (((unsigned long long)(unsigned)fj) << 32) |
                      __float_as_uint(ft));
        }
        __syncthreads();                              // bar2

        const unsigned long long wk = nxt[par];
        const int gi = (int)(wk >> 32);
        lt = __uint_as_float((unsigned)wk);
        const float2 wv = cxy[gi];                    // LDS broadcast read
        lx = wv.x; ly = wv.y;
        if (t == 0) idx_out[b * M_ + k] = gi;
    }
}

// ---------------------------------------------------------------------------
// Kernel 2: gather coords/times/polarities at sampled indices.
// ---------------------------------------------------------------------------
__global__ __launch_bounds__(256) void gather_kernel(
    const float* __restrict__ coords, const float* __restrict__ times,
    const float* __restrict__ pol, const int* __restrict__ idx,
    float* __restrict__ out)
{
    int i = blockIdx.x * 256 + threadIdx.x;       // 0 .. B_*M_-1
    if (i >= B_ * M_) return;
    int b = i >> 12;                              // / M_
    int g = b * N_ + idx[i];
    float2 c2 = *(const float2*)(coords + 2 * (size_t)g);
    *(float2*)(out + COFF + 2 * (size_t)i) = c2;
    out[TOFF + i] = times[g];
    out[POFF + i] = pol[g];
}

// ---------------------------------------------------------------------------
// Kernel 3: gathered GEMM + bias.  C[row, o] = features[src(row), :] . W[o, :]
// ---------------------------------------------------------------------------
#define BM 32
#define BN 128
#define BK 32

__global__ __launch_bounds__(256) void proj_kernel(
    const float* __restrict__ features, const float* __restrict__ W,
    const float* __restrict__ bias, const int* __restrict__ idx,
    float* __restrict__ out)
{
    __shared__ float a_lds[BK][BM + 4];
    __shared__ float w_lds[BK][BN];
    __shared__ int   src[BM];

    const int t = threadIdx.x;
    const int rowBase = blockIdx.x * BM;
    const int oBase = blockIdx.y * BN;

    if (t < BM) {
        int row = rowBase + t;
        int b = row >> 12;                // / M_
        src[t] = b * N_ + idx[row];
    }
    __syncthreads();

    const int rt = t >> 5;        // 0..7   -> rows rt*4..rt*4+3
    const int ot = t & 31;        // 0..31  -> outs ot*4..ot*4+3
    const int lr = t >> 3;        // 0..31  staging row / out
    const int lk = (t & 7) * 4;   // 0,4,...,28 staging k

    float c[4][4] = {};

    for (int kc = 0; kc < D_; kc += BK) {
        {
            float4 v = *(const float4*)(features + (size_t)src[lr] * D_ + kc + lk);
            a_lds[lk + 0][lr] = v.x; a_lds[lk + 1][lr] = v.y;
            a_lds[lk + 2][lr] = v.z; a_lds[lk + 3][lr] = v.w;
        }
#pragma unroll
        for (int p = 0; p < 4; ++p) {
            int o = p * 32 + lr;
            float4 v = *(const float4*)(W + (size_t)(oBase + o) * D_ + kc + lk);
            w_lds[lk + 0][o] = v.x; w_lds[lk + 1][o] = v.y;
            w_lds[lk + 2][o] = v.z; w_lds[lk + 3][o] = v.w;
        }
        __syncthreads();

#pragma unroll
        for (int k = 0; k < BK; ++k) {
            float4 af = *(const float4*)&a_lds[k][rt * 4];
            float4 wf = *(const float4*)&w_lds[k][ot * 4];
            float av[4] = { af.x, af.y, af.z, af.w };
            float wv[4] = { wf.x, wf.y, wf.z, wf.w };
#pragma unroll
            for (int ri = 0; ri < 4; ++ri)
#pragma unroll
                for (int oi = 0; oi < 4; ++oi)
                    c[ri][oi] = fmaf(av[ri], wv[oi], c[ri][oi]);
        }
        __syncthreads();
    }

    float4 bv = *(const float4*)(bias + oBase + ot * 4);
    float bvv[4] = { bv.x, bv.y, bv.z, bv.w };
#pragma unroll
    for (int ri = 0; ri < 4; ++ri) {
        int row = rowBase + rt * 4 + ri;
        float4 o4;
        o4.x = c[ri][0] + bvv[0];
        o4.y = c[ri][1] + bvv[1];
        o4.z = c[ri][2] + bvv[2];
        o4.w = c[ri][3] + bvv[3];
        *(float4*)(out + (size_t)row * D_ + oBase + ot * 4) = o4;
    }
}

// ---------------------------------------------------------------------------
// Kernel 4: LayerNorm in place over the proj output. One wave per row.
// ---------------------------------------------------------------------------
__global__ __launch_bounds__(256) void ln_kernel(
    float* __restrict__ out, const float* __restrict__ gamma,
    const float* __restrict__ beta)
{
    const int w = threadIdx.x >> 6;
    const int lane = threadIdx.x & 63;
    const size_t row = (size_t)blockIdx.x * 4 + w;
    float* p = out + row * D_;

    float4 v0 = *(const float4*)(p + lane * 8);
    float4 v1 = *(const float4*)(p + lane * 8 + 4);
    float x[8] = { v0.x, v0.y, v0.z, v0.w, v1.x, v1.y, v1.z, v1.w };

    float sum = 0.f;
#pragma unroll
    for (int i = 0; i < 8; ++i) sum += x[i];
#pragma unroll
    for (int off = 1; off < 64; off <<= 1) sum += __shfl_xor(sum, off);
    const float mu = sum * (1.0f / 512.0f);

    float sq = 0.f;
#pragma unroll
    for (int i = 0; i < 8; ++i) { float d = x[i] - mu; sq = fmaf(d, d, sq); }
#pragma unroll
    for (int off = 1; off < 64; off <<= 1) sq += __shfl_xor(sq, off);
    const float inv = rsqrtf(sq * (1.0f / 512.0f) + 1e-5f);

    float4 g0 = *(const float4*)(gamma + lane * 8);
    float4 g1 = *(const float4*)(gamma + lane * 8 + 4);
    float4 b0 = *(const float4*)(beta + lane * 8);
    float4 b1 = *(const float4*)(beta + lane * 8 + 4);
    float g[8] = { g0.x, g0.y, g0.z, g0.w, g1.x, g1.y, g1.z, g1.w };
    float be[8] = { b0.x, b0.y, b0.z, b0.w, b1.x, b1.y, b1.z, b1.w };

    float y[8];
#pragma unroll
    for (int i = 0; i < 8; ++i) y[i] = fmaf((x[i] - mu) * inv, g[i], be[i]);

    float4 o0 = { y[0], y[1], y[2], y[3] };
    float4 o1 = { y[4], y[5], y[6], y[7] };
    *(float4*)(p + lane * 8) = o0;
    *(float4*)(p + lane * 8 + 4) = o1;
}

// ---------------------------------------------------------------------------
extern "C" void kernel_launch(void* const* d_in, const int* in_sizes, int n_in,
                              void* d_out, int out_size, void* d_ws, size_t ws_size,
                              hipStream_t stream)
{
    const float* features   = (const float*)d_in[0];
    const float* coords     = (const float*)d_in[1];
    const float* times      = (const float*)d_in[2];
    const float* polarities = (const float*)d_in[3];
    const float* W          = (const float*)d_in[4];
    const float* bias       = (const float*)d_in[5];
    const float* gamma      = (const float*)d_in[6];
    const float* beta       = (const float*)d_in[7];
    float* out = (float*)d_out;

    int* idx = (int*)d_ws;                        // B_*M_ ints = 128 KiB scratch

    fps_kernel<<<B_, TPB, 0, stream>>>(coords, times, idx);

    gather_kernel<<<(B_ * M_ + 255) / 256, 256, 0, stream>>>(
        coords, times, polarities, idx, out);

    dim3 pgrid(B_ * M_ / BM, D_ / BN);            // (1024, 4)
    proj_kernel<<<pgrid, 256, 0, stream>>>(features, W, bias, idx, out);

    ln_kernel<<<B_ * M_ / 4, 256, 0, stream>>>(out, gamma, beta);
}